// Round 3
// baseline (595.611 us; speedup 1.0000x reference)
//
#include <hip/hip_runtime.h>

// Fused MLP: x[131072,512] -> (Linear+LN+CELU)x4 -> spectral-norm head -> [131072,1]
// R8: BISECT round. R5's proven kernel with ONLY mechanical M=32 geometry edits:
// 4096 blocks, 32-row tile, LDS ~37KB. Everything else R5-exact: launch_bounds(512,4),
// depth-4 W1 prefetch ring, single chained GEMM3 accumulator, scalar stat sums,
// software RNE f2bf, 9-barrier structure. R6/R7 (both failed) shared
// __launch_bounds__(512,6), which forces total regs <= ~85 (6 waves/EU per m69 steps)
// -> extreme-spill codegen never exercised before; this round removes that variable.
// If PASS -> (512,6) implicated; if FAIL -> M=32 geometry cursed, revert to R5 base.

typedef unsigned short u16;
typedef unsigned int   u32;
typedef __bf16  bf16x8 __attribute__((ext_vector_type(8)));
typedef float   f32x16 __attribute__((ext_vector_type(16)));

__device__ __forceinline__ u16 f2bf(float f) {           // RTN-even f32->bf16
    u32 x = __builtin_bit_cast(u32, f);
    x += 0x7FFFu + ((x >> 16) & 1u);
    return (u16)(x >> 16);
}
__device__ __forceinline__ float bfval(u16 h) { return __builtin_bit_cast(float, (u32)h << 16); }
__device__ __forceinline__ u32 pack2(float a, float b) { return (u32)f2bf(a) | ((u32)f2bf(b) << 16); }
__device__ __forceinline__ float celu1(float x) { return x > 0.f ? x : __expf(x) - 1.f; }

// ws element offsets (u16), fragment-packed layouts (all 32x32x16):
// W1F: [ksg 0..32)[ntile 0..16)[lane 0..64)[e 0..8)
// W2F: [ksg 0..32)[ntile 0..4 )[lane][e]
// W3F/W3LF: [ksg 0..8)[lane][e]  (hi / lo-residual)
#define W1F_OFF 0
#define W2F_OFF 262144
#define W3F_OFF 327680
#define W3LF_OFF 331776
#define NGROUPS 41984

__global__ void prep_weights(const float* __restrict__ W1, const float* __restrict__ W2,
                             const float* __restrict__ W3, u16* __restrict__ wsb) {
    const int g = blockIdx.x * 256 + threadIdx.x;   // 164*256 == 41984 exactly
    if (g < 32768) {                                // W1 fragments
        const int l = g & 63, t = (g >> 6) & 15, ksg = g >> 10;
        const int n = t * 32 + (l & 31);
        const int k0 = ksg * 16 + (l >> 5) * 8;
        u16* dst = wsb + W1F_OFF + g * 8;
        const float* src = W1 + n * 512 + k0;
#pragma unroll
        for (int e = 0; e < 8; ++e) dst[e] = f2bf(src[e]);
    } else if (g < 40960) {                         // W2 fragments
        const int h = g - 32768;
        const int l = h & 63, t = (h >> 6) & 3, ksg = h >> 8;
        const int n = t * 32 + (l & 31);
        const int k0 = ksg * 16 + (l >> 5) * 8;
        u16* dst = wsb + W2F_OFF + h * 8;
        const float* src = W2 + n * 512 + k0;
#pragma unroll
        for (int e = 0; e < 8; ++e) dst[e] = f2bf(src[e]);
    } else if (g < 41472) {                         // W3 hi fragments
        const int h = g - 40960;
        const int l = h & 63, ksg = h >> 6;
        const int n = l & 31;
        const int k0 = ksg * 16 + (l >> 5) * 8;
        u16* dst = wsb + W3F_OFF + h * 8;
        const float* src = W3 + n * 128 + k0;
#pragma unroll
        for (int e = 0; e < 8; ++e) dst[e] = f2bf(src[e]);
    } else {                                        // W3 lo-residual fragments
        const int h = g - 41472;
        const int l = h & 63, ksg = h >> 6;
        const int n = l & 31;
        const int k0 = ksg * 16 + (l >> 5) * 8;
        u16* dst = wsb + W3LF_OFF + h * 8;
        const float* src = W3 + n * 128 + k0;
#pragma unroll
        for (int e = 0; e < 8; ++e) { float w = src[e]; dst[e] = f2bf(w - bfval(f2bf(w))); }
    }
}

// head-param LDS layout (floats)
#define PW4 0
#define PB4 256
#define PG4 264
#define PBE4 272
#define PWH 280
#define PBH 288
#define PU  289
#define NPAR 290

__global__ __launch_bounds__(512, 4) void fused_mlp(
    const float* __restrict__ x,
    const u16* __restrict__ W1b, const u16* __restrict__ W2b,
    const u16* __restrict__ W3b, const u16* __restrict__ W3Lb,
    const float* __restrict__ b1, const float* __restrict__ g1, const float* __restrict__ be1,
    const float* __restrict__ b2, const float* __restrict__ g2, const float* __restrict__ be2,
    const float* __restrict__ b3, const float* __restrict__ g3, const float* __restrict__ be3,
    const float* __restrict__ W4, const float* __restrict__ b4, const float* __restrict__ g4,
    const float* __restrict__ be4,
    const float* __restrict__ Wh, const float* __restrict__ bh, const float* __restrict__ uvec,
    float* __restrict__ out)
{
    // Single big buffer, reused in place:
    //   phase GEMM1 : u16 cols [0,512)  = x tile (bf16)
    //   after LN1   : u16 cols [0,512)  = h1 post-act (bf16)
    //   after LN2   : u16 cols [0,128)  = h2 hi, [128,256) = h2 lo
    //   after GEMM3 : f32 idx [128,160) i.e. u16 cols [256,320) = h3f (32 floats)
    __shared__ __align__(16) u16 sXH[32][520];
    __shared__ __align__(16) float sPS[32][8];   // LN partials / h4
    __shared__ __align__(16) float sPQ[32][8];
    __shared__ __align__(8)  float2 sMR[32];     // {mu, rsqrt}
    __shared__ __align__(16) float sP[NPAR + 2]; // head params

    const int tid = threadIdx.x;
    const int wv = tid >> 6;          // wave 0..7
    const int lane = tid & 63;
    const int ln = lane & 31;
    const int lh = lane >> 5;
    const int row0 = blockIdx.x * 32;

    // ---- per-wave LN/bias params in registers (tiny, L2-hot) ----
    const float b1a = b1[wv * 64 + ln],  b1c = b1[wv * 64 + 32 + ln];
    const float g1a = g1[wv * 64 + ln],  g1c = g1[wv * 64 + 32 + ln];
    const float e1a = be1[wv * 64 + ln], e1c = be1[wv * 64 + 32 + ln];
    const int Nt2 = wv & 3;            // GEMM2 n-tile for waves 0-3
    const float b2v = b2[Nt2 * 32 + ln], g2v = g2[Nt2 * 32 + ln], e2v = be2[Nt2 * 32 + ln];
    const float b3v = b3[ln], g3v = g3[ln], e3v = be3[ln];

    // ---- stage head params ----
    if (tid < NPAR) {
        float v;
        if      (tid < 256) v = W4[tid];
        else if (tid < 264) v = b4[tid - 256];
        else if (tid < 272) v = g4[tid - 264];
        else if (tid < 280) v = be4[tid - 272];
        else if (tid < 288) v = Wh[tid - 280];
        else if (tid == 288) v = bh[0];
        else                v = uvec[0];
        sP[tid] = v;
    }

    // ---- phase0: stage whole 32-row x tile as bf16 (transient registers only) ----
    {
        const float4* xp = (const float4*)(x) + (long)blockIdx.x * 4096 + tid;
        float4 q[8];
#pragma unroll
        for (int j = 0; j < 8; ++j) q[j] = xp[j * 512];
        const int r0 = tid >> 7;           // 0..3
        const int c4 = (tid & 127) * 4;    // u16 col 0..508
#pragma unroll
        for (int j = 0; j < 8; ++j)
            *(uint2*)(&sXH[j * 4 + r0][c4]) =
                make_uint2(pack2(q[j].x, q[j].y), pack2(q[j].z, q[j].w));
    }
    __syncthreads();                       // B1: x + sP visible

    // ========== GEMM1: h1 = x @ W1^T (M=32,N=512,K=512), wave -> cols wv*64..+64 ==========
    f32x16 acc[2] = {};                    // [nt], 32x32x16 accs
    {
        const u16* wq = W1b + (wv * 2) * 512 + lane * 8;   // frag(ksg,nt) = wq + ksg*8192 + nt*512
        bf16x8 Bf[4][2];                   // R5's depth-4 ring
#pragma unroll
        for (int s = 0; s < 3; ++s) {
            Bf[s][0] = *(const bf16x8*)(wq + s * 8192);
            Bf[s][1] = *(const bf16x8*)(wq + s * 8192 + 512);
        }
#pragma unroll
        for (int ksg = 0; ksg < 32; ++ksg) {
            const int slot = ksg & 3;
            if (ksg + 3 < 32) {
                const int ps = (ksg + 3) & 3;
                const u16* np = wq + (ksg + 3) * 8192;
                Bf[ps][0] = *(const bf16x8*)(np);
                Bf[ps][1] = *(const bf16x8*)(np + 512);
            }
            bf16x8 a0 = *(const bf16x8*)(&sXH[ln][ksg * 16 + lh * 8]);
            acc[0] = __builtin_amdgcn_mfma_f32_32x32x16_bf16(a0, Bf[slot][0], acc[0], 0, 0, 0);
            acc[1] = __builtin_amdgcn_mfma_f32_32x32x16_bf16(a0, Bf[slot][1], acc[1], 0, 0, 0);
        }
    }

    // ---- LN1: fold bias, in-register butterfly row sums ----
#pragma unroll
    for (int rg = 0; rg < 16; ++rg) {
        acc[0][rg] += b1a; acc[1][rg] += b1c;
    }
#pragma unroll
    for (int rg = 0; rg < 16; ++rg) {
        float s = acc[0][rg] + acc[1][rg];
        float q = acc[0][rg] * acc[0][rg] + acc[1][rg] * acc[1][rg];
#pragma unroll
        for (int m = 1; m < 32; m <<= 1) { s += __shfl_xor(s, m, 64); q += __shfl_xor(q, m, 64); }
        if (ln == 0) {
            const int row = (rg & 3) + 8 * (rg >> 2) + 4 * lh;
            sPS[row][wv] = s; sPQ[row][wv] = q;
        }
    }
    __syncthreads();                       // B2
    if (tid < 32) {
        float s = 0.f, q = 0.f;
#pragma unroll
        for (int j = 0; j < 8; ++j) { s += sPS[tid][j]; q += sPQ[tid][j]; }
        const float mu = s * (1.f / 512.f);
        const float var = q * (1.f / 512.f) - mu * mu;
        sMR[tid] = make_float2(mu, rsqrtf(var + 1e-5f));
    }
    __syncthreads();                       // B3
    // ---- LN1 apply + CELU -> overwrite sXH with h1 (x dead) ----
#pragma unroll
    for (int rg = 0; rg < 16; ++rg) {
        const int row = (rg & 3) + 8 * (rg >> 2) + 4 * lh;
        const float2 mr = sMR[row];
        const float h0 = (acc[0][rg] - mr.x) * mr.y * g1a + e1a;
        const float h1v = (acc[1][rg] - mr.x) * mr.y * g1c + e1c;
        sXH[row][wv * 64 + ln] = f2bf(celu1(h0));
        sXH[row][wv * 64 + 32 + ln] = f2bf(celu1(h1v));
    }
    __syncthreads();                       // B4: h1 visible

    // ========== GEMM2: h2 = h1 @ W2^T (M=32,N=128,K=512), 32x32x16, waves 0-3 ==========
    float v2[16];
    if (wv < 4) {
        const u16* w2q = W2b + Nt2 * 512 + lane * 8;       // frag(ksg) = w2q + ksg*2048
        bf16x8 W2f[4];
#pragma unroll
        for (int s = 0; s < 4; ++s) W2f[s] = *(const bf16x8*)(w2q + s * 2048);
        f32x16 a2 = {}, a2b = {};
        const u16* h1p = &sXH[ln][lh * 8];
#pragma unroll
        for (int ksg = 0; ksg < 32; ++ksg) {
            const int slot = ksg & 3;
            bf16x8 af = *(const bf16x8*)(h1p + ksg * 16);
            if (ksg & 1) a2b = __builtin_amdgcn_mfma_f32_32x32x16_bf16(af, W2f[slot], a2b, 0, 0, 0);
            else         a2  = __builtin_amdgcn_mfma_f32_32x32x16_bf16(af, W2f[slot], a2, 0, 0, 0);
            if (ksg + 4 < 32) W2f[slot] = *(const bf16x8*)(w2q + (ksg + 4) * 2048);
        }
#pragma unroll
        for (int rg = 0; rg < 16; ++rg) v2[rg] = a2[rg] + a2b[rg] + b2v;
#pragma unroll
        for (int rg = 0; rg < 16; ++rg) {
            float s = v2[rg], q = v2[rg] * v2[rg];
#pragma unroll
            for (int m = 1; m < 32; m <<= 1) { s += __shfl_xor(s, m, 64); q += __shfl_xor(q, m, 64); }
            if (ln == 0) {
                const int row = (rg & 3) + 8 * (rg >> 2) + 4 * lh;
                sPS[row][Nt2] = s; sPQ[row][Nt2] = q;
            }
        }
    }
    __syncthreads();                       // B5
    if (tid < 32) {
        float s = sPS[tid][0] + sPS[tid][1] + sPS[tid][2] + sPS[tid][3];
        float q = sPQ[tid][0] + sPQ[tid][1] + sPQ[tid][2] + sPQ[tid][3];
        const float mu = s * (1.f / 128.f);
        const float var = q * (1.f / 128.f) - mu * mu;
        sMR[tid] = make_float2(mu, rsqrtf(var + 1e-5f));
    }
    __syncthreads();                       // B6
    // ---- LN2 apply + CELU -> h2 hi/lo into sXH cols [0,128)+[128,256) (h1 dead) ----
    if (wv < 4) {
        const int col = Nt2 * 32 + ln;
#pragma unroll
        for (int rg = 0; rg < 16; ++rg) {
            const int row = (rg & 3) + 8 * (rg >> 2) + 4 * lh;
            const float2 mr = sMR[row];
            const float hn = (v2[rg] - mr.x) * mr.y * g2v + e2v;
            const float a = celu1(hn);
            const u16 hi = f2bf(a);
            sXH[row][col] = hi;
            sXH[row][128 + col] = f2bf(a - bfval(hi));
        }
    }
    __syncthreads();                       // B7

    // ===== GEMM3: h3 = h2 @ W3^T (M=32,N=32,K=128), split-precision, wave 0 =====
    if (wv == 0) {
        f32x16 a3 = {};                    // R5's single chained accumulator
        const u16* w3q  = W3b  + lane * 8;
        const u16* w3lq = W3Lb + lane * 8;
        const u16* h2p  = &sXH[ln][lh * 8];
        const u16* h2lp = &sXH[ln][128 + lh * 8];
#pragma unroll
        for (int ks = 0; ks < 8; ++ks) {
            bf16x8 fa_h = *(const bf16x8*)(h2p  + ks * 16);
            bf16x8 fa_l = *(const bf16x8*)(h2lp + ks * 16);
            bf16x8 fb_h = *(const bf16x8*)(w3q  + ks * 512);
            bf16x8 fb_l = *(const bf16x8*)(w3lq + ks * 512);
            a3 = __builtin_amdgcn_mfma_f32_32x32x16_bf16(fa_h, fb_h, a3, 0, 0, 0);
            a3 = __builtin_amdgcn_mfma_f32_32x32x16_bf16(fa_h, fb_l, a3, 0, 0, 0);
            a3 = __builtin_amdgcn_mfma_f32_32x32x16_bf16(fa_l, fb_h, a3, 0, 0, 0);
        }
        // LN3 fully in-register (width 32 == ln-group) -> fp32 h3 at f32 idx [128,160)
#pragma unroll
        for (int rg = 0; rg < 16; ++rg) {
            const float v = a3[rg] + b3v;
            float s = v, q = v * v;
#pragma unroll
            for (int m = 1; m < 32; m <<= 1) { s += __shfl_xor(s, m, 64); q += __shfl_xor(q, m, 64); }
            const float mu = s * (1.f / 32.f);
            const float rs = rsqrtf(q * (1.f / 32.f) - mu * mu + 1e-5f);
            const int row = (rg & 3) + 8 * (rg >> 2) + 4 * lh;
            float* s3 = (float*)&sXH[row][0] + 128;   // u16 cols [256,320), disjoint from h2
            s3[ln] = celu1((v - mu) * rs * g3v + e3v);
        }
    }
    __syncthreads();                       // B8

    // ========== Layer4 (fp32): h4 = h3 @ W4^T + b4 (width 8) ==========
    if (tid < 256) {
        const int r = tid & 31, o = tid >> 5;
        float h[32];
        const float4* hp = (const float4*)((const float*)&sXH[r][0] + 128);
#pragma unroll
        for (int j = 0; j < 8; ++j) {
            float4 tv = hp[j];
            h[j * 4 + 0] = tv.x; h[j * 4 + 1] = tv.y; h[j * 4 + 2] = tv.z; h[j * 4 + 3] = tv.w;
        }
        float a = sP[PB4 + o];
        const float* w4 = &sP[PW4 + o * 32];
#pragma unroll
        for (int k = 0; k < 32; ++k) a += h[k] * w4[k];
        sPS[r][o] = a;
    }
    __syncthreads();                       // B9

    // ========== LN4 + CELU + spectral-norm head ==========
    if (tid < 32) {
        float v[8];
        float s = 0.f, q = 0.f;
#pragma unroll
        for (int o = 0; o < 8; ++o) { v[o] = sPS[tid][o]; s += v[o]; q += v[o] * v[o]; }
        const float mu = s * 0.125f;
        const float var = q * 0.125f - mu * mu;
        const float rs = rsqrtf(var + 1e-5f);

        float wh[8];
        const float u0 = sP[PU];
        float nv = 0.f;
#pragma unroll
        for (int o = 0; o < 8; ++o) { wh[o] = sP[PWH + o]; float tt = wh[o] * u0; nv += tt * tt; }
        nv = sqrtf(nv);
        const float inv = 1.f / (nv + 1e-12f);
        float s2 = 0.f;
#pragma unroll
        for (int o = 0; o < 8; ++o) s2 += wh[o] * (wh[o] * u0 * inv);
        const float u2 = s2 / (fabsf(s2) + 1e-12f);
        const float sigma = u2 * s2;
        const float isg = 1.f / sigma;

        float y = sP[PBH];
#pragma unroll
        for (int o = 0; o < 8; ++o) {
            const float hn = (v[o] - mu) * rs * sP[PG4 + o] + sP[PBE4 + o];
            y += celu1(hn) * wh[o] * isg;
        }
        out[row0 + tid] = y;
    }
}

extern "C" void kernel_launch(void* const* d_in, const int* in_sizes, int n_in,
                              void* d_out, int out_size, void* d_ws, size_t ws_size,
                              hipStream_t stream) {
    const float* x   = (const float*)d_in[0];
    const float* W1  = (const float*)d_in[1];
    const float* b1  = (const float*)d_in[2];
    const float* g1  = (const float*)d_in[3];
    const float* be1 = (const float*)d_in[4];
    const float* W2  = (const float*)d_in[5];
    const float* b2  = (const float*)d_in[6];
    const float* g2  = (const float*)d_in[7];
    const float* be2 = (const float*)d_in[8];
    const float* W3  = (const float*)d_in[9];
    const float* b3  = (const float*)d_in[10];
    const float* g3  = (const float*)d_in[11];
    const float* be3 = (const float*)d_in[12];
    const float* W4  = (const float*)d_in[13];
    const float* b4  = (const float*)d_in[14];
    const float* g4  = (const float*)d_in[15];
    const float* be4 = (const float*)d_in[16];
    const float* Wh  = (const float*)d_in[17];
    const float* bh  = (const float*)d_in[18];
    const float* u   = (const float*)d_in[19];
    float* out = (float*)d_out;
    u16* wsb = (u16*)d_ws;

    prep_weights<<<dim3(NGROUPS / 256), dim3(256), 0, stream>>>(W1, W2, W3, wsb);

    const int rows = in_sizes[0] / 512;       // 131072
    fused_mlp<<<dim3(rows / 32), dim3(512), 0, stream>>>(
        x, wsb + W1F_OFF, wsb + W2F_OFF, wsb + W3F_OFF, wsb + W3LF_OFF,
        b1, g1, be1, b2, g2, be2, b3, g3, be3,
        W4, b4, g4, be4, Wh, bh, u, out);
}

// Round 4
// 539.343 us; speedup vs baseline: 1.1043x; 1.1043x over previous
//
#include <hip/hip_runtime.h>

// Fused MLP: x[131072,512] -> (Linear+LN+CELU)x4 -> spectral-norm head -> [131072,1]
// R9: R5 base (M=64, 2048 blocks x 512 thr, launch_bounds(512,4), 72.7KB LDS,
// VGPR64+AGPR64 = exactly the 4-wave/SIMD boundary) + three surgical edits:
//  1. f2bf = HW v_cvt bf16 cast (RNE, bit-identical to software RNE, ~4x fewer ops).
//  2. Barrier-free tail: after B7 waves 2-7 exit; waves 0/1 run independent 32-row
//     tails (G3+LN3 R5-exact, same-wave LDS handoff via lgkmcnt(0), L4+LN4+head
//     in-register on lanes 0-31). Barriers B8/B9 eliminated (9 -> 7).
//  3. s_setprio(1) around GEMM1/GEMM2 MFMA K-loops (T5: 2 co-resident blocks at
//     skewed phases = role diversity for the CU scheduler).
// R6/R7 post-mortem: failures isolated to __launch_bounds__(512,6) extreme-regalloc
// codegen (R8 bisect passed with identical geometry at (512,4)). Never below (512,4).
// R8 lesson: register quantum (64/128 steps, m69) makes 3 blocks/CU unreachable with
// 64 acc-AGPRs -> occupancy is a dead end; this round attacks phase serialization.

typedef unsigned short u16;
typedef unsigned int   u32;
typedef __bf16  bf16x8 __attribute__((ext_vector_type(8)));
typedef float   f32x16 __attribute__((ext_vector_type(16)));

__device__ __forceinline__ u16 f2bf(float f) {           // HW RNE f32->bf16 (1 op)
    return __builtin_bit_cast(u16, (__bf16)f);
}
__device__ __forceinline__ float bfval(u16 h) { return __builtin_bit_cast(float, (u32)h << 16); }
__device__ __forceinline__ u32 pack2(float a, float b) { return (u32)f2bf(a) | ((u32)f2bf(b) << 16); }
__device__ __forceinline__ float celu1(float x) { return x > 0.f ? x : __expf(x) - 1.f; }

// ws element offsets (u16), fragment-packed layouts (all 32x32x16):
// W1F: [ksg 0..32)[ntile 0..16)[lane 0..64)[e 0..8)
// W2F: [ksg 0..32)[ntile 0..4 )[lane][e]
// W3F/W3LF: [ksg 0..8)[lane][e]  (hi / lo-residual)
#define W1F_OFF 0
#define W2F_OFF 262144
#define W3F_OFF 327680
#define W3LF_OFF 331776
#define NGROUPS 41984

__global__ void prep_weights(const float* __restrict__ W1, const float* __restrict__ W2,
                             const float* __restrict__ W3, u16* __restrict__ wsb) {
    const int g = blockIdx.x * 256 + threadIdx.x;   // 164*256 == 41984 exactly
    if (g < 32768) {                                // W1 fragments
        const int l = g & 63, t = (g >> 6) & 15, ksg = g >> 10;
        const int n = t * 32 + (l & 31);
        const int k0 = ksg * 16 + (l >> 5) * 8;
        u16* dst = wsb + W1F_OFF + g * 8;
        const float* src = W1 + n * 512 + k0;
#pragma unroll
        for (int e = 0; e < 8; ++e) dst[e] = f2bf(src[e]);
    } else if (g < 40960) {                         // W2 fragments
        const int h = g - 32768;
        const int l = h & 63, t = (h >> 6) & 3, ksg = h >> 8;
        const int n = t * 32 + (l & 31);
        const int k0 = ksg * 16 + (l >> 5) * 8;
        u16* dst = wsb + W2F_OFF + h * 8;
        const float* src = W2 + n * 512 + k0;
#pragma unroll
        for (int e = 0; e < 8; ++e) dst[e] = f2bf(src[e]);
    } else if (g < 41472) {                         // W3 hi fragments
        const int h = g - 40960;
        const int l = h & 63, ksg = h >> 6;
        const int n = l & 31;
        const int k0 = ksg * 16 + (l >> 5) * 8;
        u16* dst = wsb + W3F_OFF + h * 8;
        const float* src = W3 + n * 128 + k0;
#pragma unroll
        for (int e = 0; e < 8; ++e) dst[e] = f2bf(src[e]);
    } else {                                        // W3 lo-residual fragments
        const int h = g - 41472;
        const int l = h & 63, ksg = h >> 6;
        const int n = l & 31;
        const int k0 = ksg * 16 + (l >> 5) * 8;
        u16* dst = wsb + W3LF_OFF + h * 8;
        const float* src = W3 + n * 128 + k0;
#pragma unroll
        for (int e = 0; e < 8; ++e) { float w = src[e]; dst[e] = f2bf(w - bfval(f2bf(w))); }
    }
}

// head-param LDS layout (floats)
#define PW4 0
#define PB4 256
#define PG4 264
#define PBE4 272
#define PWH 280
#define PBH 288
#define PU  289
#define NPAR 290

__global__ __launch_bounds__(512, 4) void fused_mlp(
    const float* __restrict__ x,
    const u16* __restrict__ W1b, const u16* __restrict__ W2b,
    const u16* __restrict__ W3b, const u16* __restrict__ W3Lb,
    const float* __restrict__ b1, const float* __restrict__ g1, const float* __restrict__ be1,
    const float* __restrict__ b2, const float* __restrict__ g2, const float* __restrict__ be2,
    const float* __restrict__ b3, const float* __restrict__ g3, const float* __restrict__ be3,
    const float* __restrict__ W4, const float* __restrict__ b4, const float* __restrict__ g4,
    const float* __restrict__ be4,
    const float* __restrict__ Wh, const float* __restrict__ bh, const float* __restrict__ uvec,
    float* __restrict__ out)
{
    // Single big buffer, reused in place:
    //   phase GEMM1 : u16 cols [0,512)  = x tile (bf16)
    //   after LN1   : u16 cols [0,512)  = h1 post-act (bf16)
    //   after LN2   : u16 cols [0,128)  = h2 hi, [128,256) = h2 lo
    //   after GEMM3 : f32 idx [128,160) i.e. u16 cols [256,320) = h3f (32 floats)
    __shared__ __align__(16) u16 sXH[64][520];
    __shared__ __align__(16) float sPS[64][8];   // LN partials
    __shared__ __align__(16) float sPQ[64][8];
    __shared__ __align__(8)  float2 sMR[64];     // {mu, rsqrt}
    __shared__ __align__(16) float sP[NPAR + 2]; // head params

    const int tid = threadIdx.x;
    const int wv = tid >> 6;          // wave 0..7
    const int lane = tid & 63;
    const int ln = lane & 31;
    const int lh = lane >> 5;
    const int Ng = wv;                // GEMM1: wave covers cols Ng*64..Ng*64+63
    const int row0 = blockIdx.x * 64;

    // ---- per-wave LN/bias params in registers (tiny, L2-hot) ----
    const float b1a = b1[Ng * 64 + ln],  b1c = b1[Ng * 64 + 32 + ln];
    const float g1a = g1[Ng * 64 + ln],  g1c = g1[Ng * 64 + 32 + ln];
    const float e1a = be1[Ng * 64 + ln], e1c = be1[Ng * 64 + 32 + ln];
    const int Mt2 = wv >> 2, Nt2 = wv & 3;
    const float b2v = b2[Nt2 * 32 + ln], g2v = g2[Nt2 * 32 + ln], e2v = be2[Nt2 * 32 + ln];
    const float b3v = b3[ln], g3v = g3[ln], e3v = be3[ln];

    // ---- stage head params ----
    if (tid < NPAR) {
        float v;
        if      (tid < 256) v = W4[tid];
        else if (tid < 264) v = b4[tid - 256];
        else if (tid < 272) v = g4[tid - 264];
        else if (tid < 280) v = be4[tid - 272];
        else if (tid < 288) v = Wh[tid - 280];
        else if (tid == 288) v = bh[0];
        else                v = uvec[0];
        sP[tid] = v;
    }

    // ---- phase0: stage whole x tile as bf16 (transient registers only) ----
    {
        const float4* xp = (const float4*)(x) + (long)blockIdx.x * 8192 + tid;
        float4 q[16];
#pragma unroll
        for (int j = 0; j < 16; ++j) q[j] = xp[j * 512];
        const int r0 = tid >> 7;           // 0..3
        const int c4 = (tid & 127) * 4;    // u16 col 0..508
#pragma unroll
        for (int j = 0; j < 16; ++j)
            *(uint2*)(&sXH[j * 4 + r0][c4]) =
                make_uint2(pack2(q[j].x, q[j].y), pack2(q[j].z, q[j].w));
    }
    __syncthreads();                       // B1: x + sP visible

    // ================= GEMM1: h1 = x @ W1^T (M=64,N=512,K=512), barrier-free =================
    f32x16 acc[2][2] = {};                 // [mt][nt]
    {
        const u16* wq = W1b + (Ng * 2) * 512 + lane * 8;   // frag(ksg,nt) = wq + ksg*8192 + nt*512
        bf16x8 Bf[4][2];
#pragma unroll
        for (int s = 0; s < 3; ++s) {
            Bf[s][0] = *(const bf16x8*)(wq + s * 8192);
            Bf[s][1] = *(const bf16x8*)(wq + s * 8192 + 512);
        }
        __builtin_amdgcn_s_setprio(1);
#pragma unroll
        for (int ksg = 0; ksg < 32; ++ksg) {
            const int slot = ksg & 3;
            if (ksg + 3 < 32) {
                const int ps = (ksg + 3) & 3;
                const u16* np = wq + (ksg + 3) * 8192;
                Bf[ps][0] = *(const bf16x8*)(np);
                Bf[ps][1] = *(const bf16x8*)(np + 512);
            }
            bf16x8 a0 = *(const bf16x8*)(&sXH[ln][ksg * 16 + lh * 8]);
            bf16x8 a1 = *(const bf16x8*)(&sXH[32 + ln][ksg * 16 + lh * 8]);
            acc[0][0] = __builtin_amdgcn_mfma_f32_32x32x16_bf16(a0, Bf[slot][0], acc[0][0], 0, 0, 0);
            acc[0][1] = __builtin_amdgcn_mfma_f32_32x32x16_bf16(a0, Bf[slot][1], acc[0][1], 0, 0, 0);
            acc[1][0] = __builtin_amdgcn_mfma_f32_32x32x16_bf16(a1, Bf[slot][0], acc[1][0], 0, 0, 0);
            acc[1][1] = __builtin_amdgcn_mfma_f32_32x32x16_bf16(a1, Bf[slot][1], acc[1][1], 0, 0, 0);
        }
        __builtin_amdgcn_s_setprio(0);
    }

    // ---- LN1: fold bias, in-register butterfly row sums ----
#pragma unroll
    for (int rg = 0; rg < 16; ++rg) {
        acc[0][0][rg] += b1a; acc[0][1][rg] += b1c;
        acc[1][0][rg] += b1a; acc[1][1][rg] += b1c;
    }
#pragma unroll
    for (int mt = 0; mt < 2; ++mt)
#pragma unroll
    for (int rg = 0; rg < 16; ++rg) {
        float s = acc[mt][0][rg] + acc[mt][1][rg];
        float q = acc[mt][0][rg] * acc[mt][0][rg] + acc[mt][1][rg] * acc[mt][1][rg];
#pragma unroll
        for (int m = 1; m < 32; m <<= 1) { s += __shfl_xor(s, m, 64); q += __shfl_xor(q, m, 64); }
        if (ln == 0) {
            const int row = mt * 32 + (rg & 3) + 8 * (rg >> 2) + 4 * lh;
            sPS[row][Ng] = s; sPQ[row][Ng] = q;
        }
    }
    __syncthreads();                       // B2
    if (tid < 64) {
        float s = 0.f, q = 0.f;
#pragma unroll
        for (int j = 0; j < 8; ++j) { s += sPS[tid][j]; q += sPQ[tid][j]; }
        const float mu = s * (1.f / 512.f);
        const float var = q * (1.f / 512.f) - mu * mu;
        sMR[tid] = make_float2(mu, rsqrtf(var + 1e-5f));
    }
    __syncthreads();                       // B3
    // ---- LN1 apply + CELU -> overwrite sXH with h1 (x dead) ----
#pragma unroll
    for (int mt = 0; mt < 2; ++mt)
#pragma unroll
    for (int rg = 0; rg < 16; ++rg) {
        const int row = mt * 32 + (rg & 3) + 8 * (rg >> 2) + 4 * lh;
        const float2 mr = sMR[row];
        const float h0 = (acc[mt][0][rg] - mr.x) * mr.y * g1a + e1a;
        const float h1v = (acc[mt][1][rg] - mr.x) * mr.y * g1c + e1c;
        sXH[row][Ng * 64 + ln] = f2bf(celu1(h0));
        sXH[row][Ng * 64 + 32 + ln] = f2bf(celu1(h1v));
    }
    __syncthreads();                       // B4: h1 visible

    // ================= GEMM2: h2 = h1 @ W2^T (M=64,N=128,K=512) =================
    float v2[16];
    {
        const u16* w2q = W2b + Nt2 * 512 + lane * 8;   // frag(ksg) = w2q + ksg*2048
        bf16x8 W2f[4];
#pragma unroll
        for (int s = 0; s < 4; ++s) W2f[s] = *(const bf16x8*)(w2q + s * 2048);
        f32x16 a2 = {}, a2b = {};
        const u16* h1p = &sXH[Mt2 * 32 + ln][lh * 8];
        __builtin_amdgcn_s_setprio(1);
#pragma unroll
        for (int ksg = 0; ksg < 32; ++ksg) {
            const int slot = ksg & 3;
            bf16x8 af = *(const bf16x8*)(h1p + ksg * 16);
            if (ksg & 1) a2b = __builtin_amdgcn_mfma_f32_32x32x16_bf16(af, W2f[slot], a2b, 0, 0, 0);
            else         a2  = __builtin_amdgcn_mfma_f32_32x32x16_bf16(af, W2f[slot], a2, 0, 0, 0);
            if (ksg + 4 < 32) W2f[slot] = *(const bf16x8*)(w2q + (ksg + 4) * 2048);
        }
        __builtin_amdgcn_s_setprio(0);
#pragma unroll
        for (int rg = 0; rg < 16; ++rg) v2[rg] = a2[rg] + a2b[rg] + b2v;
#pragma unroll
        for (int rg = 0; rg < 16; ++rg) {
            float s = v2[rg], q = v2[rg] * v2[rg];
#pragma unroll
            for (int m = 1; m < 32; m <<= 1) { s += __shfl_xor(s, m, 64); q += __shfl_xor(q, m, 64); }
            if (ln == 0) {
                const int row = Mt2 * 32 + (rg & 3) + 8 * (rg >> 2) + 4 * lh;
                sPS[row][Nt2] = s; sPQ[row][Nt2] = q;
            }
        }
    }
    __syncthreads();                       // B5
    if (tid < 64) {
        float s = sPS[tid][0] + sPS[tid][1] + sPS[tid][2] + sPS[tid][3];
        float q = sPQ[tid][0] + sPQ[tid][1] + sPQ[tid][2] + sPQ[tid][3];
        const float mu = s * (1.f / 128.f);
        const float var = q * (1.f / 128.f) - mu * mu;
        sMR[tid] = make_float2(mu, rsqrtf(var + 1e-5f));
    }
    __syncthreads();                       // B6
    // ---- LN2 apply + CELU -> h2 hi/lo into sXH cols [0,128)+[128,256) (h1 dead) ----
    {
        const int col = Nt2 * 32 + ln;
#pragma unroll
        for (int rg = 0; rg < 16; ++rg) {
            const int row = Mt2 * 32 + (rg & 3) + 8 * (rg >> 2) + 4 * lh;
            const float2 mr = sMR[row];
            const float hn = (v2[rg] - mr.x) * mr.y * g2v + e2v;
            const float a = celu1(hn);
            const u16 hi = f2bf(a);
            sXH[row][col] = hi;
            sXH[row][128 + col] = f2bf(a - bfval(hi));
        }
    }
    __syncthreads();                       // B7: h2 visible — LAST barrier

    // ===== Barrier-free tail: waves 2-7 exit; waves 0/1 own rows wv*32..wv*32+31 =====
    if (wv >= 2) return;

    // ---- GEMM3: h3 = h2 @ W3^T (M=32/wave, N=32, K=128), split-precision ----
    {
        f32x16 a3 = {};                    // R5's single chained accumulator (bit-exact)
        const u16* w3q  = W3b  + lane * 8;
        const u16* w3lq = W3Lb + lane * 8;
        const u16* h2p  = &sXH[wv * 32 + ln][lh * 8];
        const u16* h2lp = &sXH[wv * 32 + ln][128 + lh * 8];
#pragma unroll
        for (int ks = 0; ks < 8; ++ks) {
            bf16x8 fa_h = *(const bf16x8*)(h2p  + ks * 16);
            bf16x8 fa_l = *(const bf16x8*)(h2lp + ks * 16);
            bf16x8 fb_h = *(const bf16x8*)(w3q  + ks * 512);
            bf16x8 fb_l = *(const bf16x8*)(w3lq + ks * 512);
            a3 = __builtin_amdgcn_mfma_f32_32x32x16_bf16(fa_h, fb_h, a3, 0, 0, 0);
            a3 = __builtin_amdgcn_mfma_f32_32x32x16_bf16(fa_h, fb_l, a3, 0, 0, 0);
            a3 = __builtin_amdgcn_mfma_f32_32x32x16_bf16(fa_l, fb_h, a3, 0, 0, 0);
        }
        // LN3 fully in-register (width 32 == ln-group) -> fp32 h3 at f32 idx [128,160)
#pragma unroll
        for (int rg = 0; rg < 16; ++rg) {
            const float v = a3[rg] + b3v;
            float s = v, q = v * v;
#pragma unroll
            for (int m = 1; m < 32; m <<= 1) { s += __shfl_xor(s, m, 64); q += __shfl_xor(q, m, 64); }
            const float mu = s * (1.f / 32.f);
            const float rs = rsqrtf(q * (1.f / 32.f) - mu * mu + 1e-5f);
            const int row = wv * 32 + (rg & 3) + 8 * (rg >> 2) + 4 * lh;
            float* s3 = (float*)&sXH[row][0] + 128;   // u16 cols [256,320), disjoint from h2
            s3[ln] = celu1((v - mu) * rs * g3v + e3v);
        }
    }
    // same-wave LDS handoff (h3 writes -> h3 reads), no cross-wave dependency
    __asm__ volatile("s_waitcnt lgkmcnt(0)" ::: "memory");

    // ---- Layer4 (fp32) + LN4 + CELU + spectral-norm head, lanes 0-31 (lane = row) ----
    if (lane < 32) {
        const int r = wv * 32 + lane;
        float h[32];
        const float4* hp = (const float4*)((const float*)&sXH[r][0] + 128);
#pragma unroll
        for (int j = 0; j < 8; ++j) {
            float4 tv = hp[j];
            h[j * 4 + 0] = tv.x; h[j * 4 + 1] = tv.y; h[j * 4 + 2] = tv.z; h[j * 4 + 3] = tv.w;
        }
        float v[8];
        float s = 0.f, q = 0.f;
#pragma unroll
        for (int o = 0; o < 8; ++o) {
            float a = sP[PB4 + o];
            const float* w4 = &sP[PW4 + o * 32];
#pragma unroll
            for (int k = 0; k < 32; ++k) a += h[k] * w4[k];
            v[o] = a; s += a; q += a * a;
        }
        const float mu = s * 0.125f;
        const float var = q * 0.125f - mu * mu;
        const float rs = rsqrtf(var + 1e-5f);

        float wh[8];
        const float u0 = sP[PU];
        float nv = 0.f;
#pragma unroll
        for (int o = 0; o < 8; ++o) { wh[o] = sP[PWH + o]; float tt = wh[o] * u0; nv += tt * tt; }
        nv = sqrtf(nv);
        const float inv = 1.f / (nv + 1e-12f);
        float s2 = 0.f;
#pragma unroll
        for (int o = 0; o < 8; ++o) s2 += wh[o] * (wh[o] * u0 * inv);
        const float u2 = s2 / (fabsf(s2) + 1e-12f);
        const float sigma = u2 * s2;
        const float isg = 1.f / sigma;

        float y = sP[PBH];
#pragma unroll
        for (int o = 0; o < 8; ++o) {
            const float hn = (v[o] - mu) * rs * sP[PG4 + o] + sP[PBE4 + o];
            y += celu1(hn) * wh[o] * isg;
        }
        out[row0 + r] = y;
    }
}

extern "C" void kernel_launch(void* const* d_in, const int* in_sizes, int n_in,
                              void* d_out, int out_size, void* d_ws, size_t ws_size,
                              hipStream_t stream) {
    const float* x   = (const float*)d_in[0];
    const float* W1  = (const float*)d_in[1];
    const float* b1  = (const float*)d_in[2];
    const float* g1  = (const float*)d_in[3];
    const float* be1 = (const float*)d_in[4];
    const float* W2  = (const float*)d_in[5];
    const float* b2  = (const float*)d_in[6];
    const float* g2  = (const float*)d_in[7];
    const float* be2 = (const float*)d_in[8];
    const float* W3  = (const float*)d_in[9];
    const float* b3  = (const float*)d_in[10];
    const float* g3  = (const float*)d_in[11];
    const float* be3 = (const float*)d_in[12];
    const float* W4  = (const float*)d_in[13];
    const float* b4  = (const float*)d_in[14];
    const float* g4  = (const float*)d_in[15];
    const float* be4 = (const float*)d_in[16];
    const float* Wh  = (const float*)d_in[17];
    const float* bh  = (const float*)d_in[18];
    const float* u   = (const float*)d_in[19];
    float* out = (float*)d_out;
    u16* wsb = (u16*)d_ws;

    prep_weights<<<dim3(NGROUPS / 256), dim3(256), 0, stream>>>(W1, W2, W3, wsb);

    const int rows = in_sizes[0] / 512;       // 131072
    fused_mlp<<<dim3(rows / 64), dim3(512), 0, stream>>>(
        x, wsb + W1F_OFF, wsb + W2F_OFF, wsb + W3F_OFF, wsb + W3LF_OFF,
        b1, g1, be1, b2, g2, be2, b3, g3, be3,
        W4, b4, g4, be4, Wh, bh, u, out);
}

// Round 6
// 512.703 us; speedup vs baseline: 1.1617x; 1.0520x over previous
//
#include <hip/hip_runtime.h>

// Fused MLP: x[131072,512] -> (Linear+LN+CELU)x4 -> spectral-norm head -> [131072,1]
// R11 = R10 with the GEMM1 ring bug fixed. R10's depth-2 ring prefetched ksg+2 into
// slot (ksg&1) BEFORE the MFMAs consumed it ((ksg+2)&1 == ksg&1) -> every k-slice
// used wrong weights (absmax 3.3). Fix: MFMAs first, prefetch after (R7's proven
// ordering). Structure: 4096 blocks x 256 thr (4 waves), 32-row tile, LDS ~36KB ->
// 4 blocks/CU co-resident = 4 independent barrier domains (vs R9's 2) at the same
// 16 waves/CU; each barrier stalls only 1/4 of the CU. Per-wave GEMM1 = 32x128
// (4 n-tiles, acc[4] = 64 AGPR). Keeps R9 wins: HW bf16 cast, setprio, barrier-free
// wave-0 tail. RING RULE (learned R10): with a depth-D ring at prefetch distance D,
// the prefetch MUST come after the uses in program order.

typedef unsigned short u16;
typedef unsigned int   u32;
typedef __bf16  bf16x8 __attribute__((ext_vector_type(8)));
typedef float   f32x16 __attribute__((ext_vector_type(16)));

__device__ __forceinline__ u16 f2bf(float f) {           // HW RNE f32->bf16 (1 op)
    return __builtin_bit_cast(u16, (__bf16)f);
}
__device__ __forceinline__ float bfval(u16 h) { return __builtin_bit_cast(float, (u32)h << 16); }
__device__ __forceinline__ u32 pack2(float a, float b) { return (u32)f2bf(a) | ((u32)f2bf(b) << 16); }
__device__ __forceinline__ float celu1(float x) { return x > 0.f ? x : __expf(x) - 1.f; }

// ws element offsets (u16), fragment-packed layouts (all 32x32x16):
// W1F: [ksg 0..32)[ntile 0..16)[lane 0..64)[e 0..8)
// W2F: [ksg 0..32)[ntile 0..4 )[lane][e]
// W3F/W3LF: [ksg 0..8)[lane][e]  (hi / lo-residual)
#define W1F_OFF 0
#define W2F_OFF 262144
#define W3F_OFF 327680
#define W3LF_OFF 331776
#define NGROUPS 41984

__global__ void prep_weights(const float* __restrict__ W1, const float* __restrict__ W2,
                             const float* __restrict__ W3, u16* __restrict__ wsb) {
    const int g = blockIdx.x * 256 + threadIdx.x;   // 164*256 == 41984 exactly
    if (g < 32768) {                                // W1 fragments
        const int l = g & 63, t = (g >> 6) & 15, ksg = g >> 10;
        const int n = t * 32 + (l & 31);
        const int k0 = ksg * 16 + (l >> 5) * 8;
        u16* dst = wsb + W1F_OFF + g * 8;
        const float* src = W1 + n * 512 + k0;
#pragma unroll
        for (int e = 0; e < 8; ++e) dst[e] = f2bf(src[e]);
    } else if (g < 40960) {                         // W2 fragments
        const int h = g - 32768;
        const int l = h & 63, t = (h >> 6) & 3, ksg = h >> 8;
        const int n = t * 32 + (l & 31);
        const int k0 = ksg * 16 + (l >> 5) * 8;
        u16* dst = wsb + W2F_OFF + h * 8;
        const float* src = W2 + n * 512 + k0;
#pragma unroll
        for (int e = 0; e < 8; ++e) dst[e] = f2bf(src[e]);
    } else if (g < 41472) {                         // W3 hi fragments
        const int h = g - 40960;
        const int l = h & 63, ksg = h >> 6;
        const int n = l & 31;
        const int k0 = ksg * 16 + (l >> 5) * 8;
        u16* dst = wsb + W3F_OFF + h * 8;
        const float* src = W3 + n * 128 + k0;
#pragma unroll
        for (int e = 0; e < 8; ++e) dst[e] = f2bf(src[e]);
    } else {                                        // W3 lo-residual fragments
        const int h = g - 41472;
        const int l = h & 63, ksg = h >> 6;
        const int n = l & 31;
        const int k0 = ksg * 16 + (l >> 5) * 8;
        u16* dst = wsb + W3LF_OFF + h * 8;
        const float* src = W3 + n * 128 + k0;
#pragma unroll
        for (int e = 0; e < 8; ++e) { float w = src[e]; dst[e] = f2bf(w - bfval(f2bf(w))); }
    }
}

// head-param LDS layout (floats)
#define PW4 0
#define PB4 256
#define PG4 264
#define PBE4 272
#define PWH 280
#define PBH 288
#define PU  289
#define NPAR 290

__global__ __launch_bounds__(256, 4) void fused_mlp(
    const float* __restrict__ x,
    const u16* __restrict__ W1b, const u16* __restrict__ W2b,
    const u16* __restrict__ W3b, const u16* __restrict__ W3Lb,
    const float* __restrict__ b1, const float* __restrict__ g1, const float* __restrict__ be1,
    const float* __restrict__ b2, const float* __restrict__ g2, const float* __restrict__ be2,
    const float* __restrict__ b3, const float* __restrict__ g3, const float* __restrict__ be3,
    const float* __restrict__ W4, const float* __restrict__ b4, const float* __restrict__ g4,
    const float* __restrict__ be4,
    const float* __restrict__ Wh, const float* __restrict__ bh, const float* __restrict__ uvec,
    float* __restrict__ out)
{
    // Single big buffer, reused in place (32-row tile):
    //   phase GEMM1 : u16 cols [0,512)  = x tile (bf16)
    //   after LN1   : u16 cols [0,512)  = h1 post-act (bf16)
    //   after LN2   : u16 cols [0,128)  = h2 hi, [128,256) = h2 lo
    //   after GEMM3 : f32 idx [128,160) i.e. u16 cols [256,320) = h3f (32 floats)
    __shared__ __align__(16) u16 sXH[32][520];
    __shared__ __align__(16) float sPS[32][4];   // LN partials (4 waves)
    __shared__ __align__(16) float sPQ[32][4];
    __shared__ __align__(8)  float2 sMR[32];     // {mu, rsqrt}
    __shared__ __align__(16) float sP[NPAR + 2]; // head params

    const int tid = threadIdx.x;
    const int wv = tid >> 6;          // wave 0..3
    const int lane = tid & 63;
    const int ln = lane & 31;
    const int lh = lane >> 5;
    const int row0 = blockIdx.x * 32;

    // ---- per-wave LN/bias params in registers (tiny, L2-hot) ----
    float b1v[4], g1v[4], e1v[4];
#pragma unroll
    for (int nt = 0; nt < 4; ++nt) {
        b1v[nt] = b1[wv * 128 + nt * 32 + ln];
        g1v[nt] = g1[wv * 128 + nt * 32 + ln];
        e1v[nt] = be1[wv * 128 + nt * 32 + ln];
    }
    const float b2v = b2[wv * 32 + ln], g2v = g2[wv * 32 + ln], e2v = be2[wv * 32 + ln];
    const float b3v = b3[ln], g3v = g3[ln], e3v = be3[ln];

    // ---- stage head params (256 threads, 2 passes) ----
    for (int i = tid; i < NPAR; i += 256) {
        float v;
        if      (i < 256) v = W4[i];
        else if (i < 264) v = b4[i - 256];
        else if (i < 272) v = g4[i - 264];
        else if (i < 280) v = be4[i - 272];
        else if (i < 288) v = Wh[i - 280];
        else if (i == 288) v = bh[0];
        else               v = uvec[0];
        sP[i] = v;
    }

    // ---- phase0: stage 32-row x tile as bf16 (transient registers only) ----
    {
        const float4* xp = (const float4*)(x) + (long)blockIdx.x * 4096 + tid;
        float4 q[16];
#pragma unroll
        for (int j = 0; j < 16; ++j) q[j] = xp[j * 256];
        const int r0 = tid >> 7;           // 0..1
        const int c4 = (tid & 127) * 4;    // u16 col 0..508
#pragma unroll
        for (int j = 0; j < 16; ++j)
            *(uint2*)(&sXH[j * 2 + r0][c4]) =
                make_uint2(pack2(q[j].x, q[j].y), pack2(q[j].z, q[j].w));
    }
    __syncthreads();                       // B1: x + sP visible

    // ====== GEMM1: h1 = x @ W1^T (M=32,N=512,K=512), wave -> cols wv*128..+127 ======
    f32x16 acc[4] = {};                    // [nt], 32x32x16 accs (64 AGPR)
    {
        const u16* wq = W1b + (wv * 4) * 512 + lane * 8;   // frag(ksg,nt) = wq + ksg*8192 + nt*512
        bf16x8 Bf[2][4];                   // depth-2 ring x 4 n-tiles (32 VGPR)
#pragma unroll
        for (int s = 0; s < 2; ++s)
#pragma unroll
            for (int nt = 0; nt < 4; ++nt)
                Bf[s][nt] = *(const bf16x8*)(wq + s * 8192 + nt * 512);
        __builtin_amdgcn_s_setprio(1);
#pragma unroll
        for (int ksg = 0; ksg < 32; ++ksg) {
            const int slot = ksg & 1;
            bf16x8 a0 = *(const bf16x8*)(&sXH[ln][ksg * 16 + lh * 8]);
            // USE first (Bf[slot] holds ksg's fragments) ...
            acc[0] = __builtin_amdgcn_mfma_f32_32x32x16_bf16(a0, Bf[slot][0], acc[0], 0, 0, 0);
            acc[1] = __builtin_amdgcn_mfma_f32_32x32x16_bf16(a0, Bf[slot][1], acc[1], 0, 0, 0);
            acc[2] = __builtin_amdgcn_mfma_f32_32x32x16_bf16(a0, Bf[slot][2], acc[2], 0, 0, 0);
            acc[3] = __builtin_amdgcn_mfma_f32_32x32x16_bf16(a0, Bf[slot][3], acc[3], 0, 0, 0);
            // ... THEN prefetch ksg+2 into the slot just freed (consumed at ksg+2).
            if (ksg + 2 < 32) {
                const u16* np = wq + (ksg + 2) * 8192;
#pragma unroll
                for (int nt = 0; nt < 4; ++nt)
                    Bf[slot][nt] = *(const bf16x8*)(np + nt * 512);
            }
        }
        __builtin_amdgcn_s_setprio(0);
    }

    // ---- LN1: fold bias, in-register butterfly row sums ----
#pragma unroll
    for (int nt = 0; nt < 4; ++nt)
#pragma unroll
        for (int rg = 0; rg < 16; ++rg) acc[nt][rg] += b1v[nt];
#pragma unroll
    for (int rg = 0; rg < 16; ++rg) {
        float s = acc[0][rg] + acc[1][rg] + acc[2][rg] + acc[3][rg];
        float q = acc[0][rg] * acc[0][rg] + acc[1][rg] * acc[1][rg]
                + acc[2][rg] * acc[2][rg] + acc[3][rg] * acc[3][rg];
#pragma unroll
        for (int m = 1; m < 32; m <<= 1) { s += __shfl_xor(s, m, 64); q += __shfl_xor(q, m, 64); }
        if (ln == 0) {
            const int row = (rg & 3) + 8 * (rg >> 2) + 4 * lh;
            sPS[row][wv] = s; sPQ[row][wv] = q;
        }
    }
    __syncthreads();                       // B2
    if (tid < 32) {
        const float s = sPS[tid][0] + sPS[tid][1] + sPS[tid][2] + sPS[tid][3];
        const float q = sPQ[tid][0] + sPQ[tid][1] + sPQ[tid][2] + sPQ[tid][3];
        const float mu = s * (1.f / 512.f);
        const float var = q * (1.f / 512.f) - mu * mu;
        sMR[tid] = make_float2(mu, rsqrtf(var + 1e-5f));
    }
    __syncthreads();                       // B3
    // ---- LN1 apply + CELU -> overwrite sXH with h1 (x dead) ----
#pragma unroll
    for (int rg = 0; rg < 16; ++rg) {
        const int row = (rg & 3) + 8 * (rg >> 2) + 4 * lh;
        const float2 mr = sMR[row];
#pragma unroll
        for (int nt = 0; nt < 4; ++nt) {
            const float h0 = (acc[nt][rg] - mr.x) * mr.y * g1v[nt] + e1v[nt];
            sXH[row][wv * 128 + nt * 32 + ln] = f2bf(celu1(h0));
        }
    }
    __syncthreads();                       // B4: h1 visible

    // ====== GEMM2: h2 = h1 @ W2^T (M=32,N=128,K=512), wave -> n-tile wv ======
    float v2[16];
    {
        const u16* w2q = W2b + wv * 512 + lane * 8;    // frag(ksg) = w2q + ksg*2048
        bf16x8 W2f[4];
#pragma unroll
        for (int s = 0; s < 4; ++s) W2f[s] = *(const bf16x8*)(w2q + s * 2048);
        f32x16 a2 = {}, a2b = {};
        const u16* h1p = &sXH[ln][lh * 8];
        __builtin_amdgcn_s_setprio(1);
#pragma unroll
        for (int ksg = 0; ksg < 32; ++ksg) {
            const int slot = ksg & 3;
            bf16x8 af = *(const bf16x8*)(h1p + ksg * 16);
            if (ksg & 1) a2b = __builtin_amdgcn_mfma_f32_32x32x16_bf16(af, W2f[slot], a2b, 0, 0, 0);
            else         a2  = __builtin_amdgcn_mfma_f32_32x32x16_bf16(af, W2f[slot], a2, 0, 0, 0);
            if (ksg + 4 < 32) W2f[slot] = *(const bf16x8*)(w2q + (ksg + 4) * 2048);
        }
        __builtin_amdgcn_s_setprio(0);
#pragma unroll
        for (int rg = 0; rg < 16; ++rg) v2[rg] = a2[rg] + a2b[rg] + b2v;
#pragma unroll
        for (int rg = 0; rg < 16; ++rg) {
            float s = v2[rg], q = v2[rg] * v2[rg];
#pragma unroll
            for (int m = 1; m < 32; m <<= 1) { s += __shfl_xor(s, m, 64); q += __shfl_xor(q, m, 64); }
            if (ln == 0) {
                const int row = (rg & 3) + 8 * (rg >> 2) + 4 * lh;
                sPS[row][wv] = s; sPQ[row][wv] = q;
            }
        }
    }
    __syncthreads();                       // B5
    if (tid < 32) {
        const float s = sPS[tid][0] + sPS[tid][1] + sPS[tid][2] + sPS[tid][3];
        const float q = sPQ[tid][0] + sPQ[tid][1] + sPQ[tid][2] + sPQ[tid][3];
        const float mu = s * (1.f / 128.f);
        const float var = q * (1.f / 128.f) - mu * mu;
        sMR[tid] = make_float2(mu, rsqrtf(var + 1e-5f));
    }
    __syncthreads();                       // B6
    // ---- LN2 apply + CELU -> h2 hi/lo into sXH cols [0,128)+[128,256) (h1 dead) ----
    {
        const int col = wv * 32 + ln;
#pragma unroll
        for (int rg = 0; rg < 16; ++rg) {
            const int row = (rg & 3) + 8 * (rg >> 2) + 4 * lh;
            const float2 mr = sMR[row];
            const float hn = (v2[rg] - mr.x) * mr.y * g2v + e2v;
            const float a = celu1(hn);
            const u16 hi = f2bf(a);
            sXH[row][col] = hi;
            sXH[row][128 + col] = f2bf(a - bfval(hi));
        }
    }
    __syncthreads();                       // B7: h2 visible — LAST barrier

    // ===== Barrier-free tail: waves 1-3 exit; wave 0 owns all 32 rows =====
    if (wv != 0) return;

    // ---- GEMM3: h3 = h2 @ W3^T (M=32,N=32,K=128), split-precision ----
    {
        f32x16 a3 = {};                    // single chained accumulator (R5/R8-exact)
        const u16* w3q  = W3b  + lane * 8;
        const u16* w3lq = W3Lb + lane * 8;
        const u16* h2p  = &sXH[ln][lh * 8];
        const u16* h2lp = &sXH[ln][128 + lh * 8];
#pragma unroll
        for (int ks = 0; ks < 8; ++ks) {
            bf16x8 fa_h = *(const bf16x8*)(h2p  + ks * 16);
            bf16x8 fa_l = *(const bf16x8*)(h2lp + ks * 16);
            bf16x8 fb_h = *(const bf16x8*)(w3q  + ks * 512);
            bf16x8 fb_l = *(const bf16x8*)(w3lq + ks * 512);
            a3 = __builtin_amdgcn_mfma_f32_32x32x16_bf16(fa_h, fb_h, a3, 0, 0, 0);
            a3 = __builtin_amdgcn_mfma_f32_32x32x16_bf16(fa_h, fb_l, a3, 0, 0, 0);
            a3 = __builtin_amdgcn_mfma_f32_32x32x16_bf16(fa_l, fb_h, a3, 0, 0, 0);
        }
        // LN3 fully in-register (width 32 == ln-group) -> fp32 h3 at f32 idx [128,160)
#pragma unroll
        for (int rg = 0; rg < 16; ++rg) {
            const float v = a3[rg] + b3v;
            float s = v, q = v * v;
#pragma unroll
            for (int m = 1; m < 32; m <<= 1) { s += __shfl_xor(s, m, 64); q += __shfl_xor(q, m, 64); }
            const float mu = s * (1.f / 32.f);
            const float rs = rsqrtf(q * (1.f / 32.f) - mu * mu + 1e-5f);
            const int row = (rg & 3) + 8 * (rg >> 2) + 4 * lh;
            float* s3 = (float*)&sXH[row][0] + 128;   // u16 cols [256,320), disjoint from h2
            s3[ln] = celu1((v - mu) * rs * g3v + e3v);
        }
    }
    // same-wave LDS handoff (h3 writes -> h3 reads), no cross-wave dependency
    __asm__ volatile("s_waitcnt lgkmcnt(0)" ::: "memory");

    // ---- Layer4 (fp32) + LN4 + CELU + spectral-norm head, lanes 0-31 (lane = row) ----
    if (lane < 32) {
        const int r = lane;
        float h[32];
        const float4* hp = (const float4*)((const float*)&sXH[r][0] + 128);
#pragma unroll
        for (int j = 0; j < 8; ++j) {
            float4 tv = hp[j];
            h[j * 4 + 0] = tv.x; h[j * 4 + 1] = tv.y; h[j * 4 + 2] = tv.z; h[j * 4 + 3] = tv.w;
        }
        float v[8];
        float s = 0.f, q = 0.f;
#pragma unroll
        for (int o = 0; o < 8; ++o) {
            float a = sP[PB4 + o];
            const float* w4 = &sP[PW4 + o * 32];
#pragma unroll
            for (int k = 0; k < 32; ++k) a += h[k] * w4[k];
            v[o] = a; s += a; q += a * a;
        }
        const float mu = s * 0.125f;
        const float var = q * 0.125f - mu * mu;
        const float rs = rsqrtf(var + 1e-5f);

        float wh[8];
        const float u0 = sP[PU];
        float nv = 0.f;
#pragma unroll
        for (int o = 0; o < 8; ++o) { wh[o] = sP[PWH + o]; float tt = wh[o] * u0; nv += tt * tt; }
        nv = sqrtf(nv);
        const float inv = 1.f / (nv + 1e-12f);
        float s2 = 0.f;
#pragma unroll
        for (int o = 0; o < 8; ++o) s2 += wh[o] * (wh[o] * u0 * inv);
        const float u2 = s2 / (fabsf(s2) + 1e-12f);
        const float sigma = u2 * s2;
        const float isg = 1.f / sigma;

        float y = sP[PBH];
#pragma unroll
        for (int o = 0; o < 8; ++o) {
            const float hn = (v[o] - mu) * rs * sP[PG4 + o] + sP[PBE4 + o];
            y += celu1(hn) * wh[o] * isg;
        }
        out[row0 + r] = y;
    }
}

extern "C" void kernel_launch(void* const* d_in, const int* in_sizes, int n_in,
                              void* d_out, int out_size, void* d_ws, size_t ws_size,
                              hipStream_t stream) {
    const float* x   = (const float*)d_in[0];
    const float* W1  = (const float*)d_in[1];
    const float* b1  = (const float*)d_in[2];
    const float* g1  = (const float*)d_in[3];
    const float* be1 = (const float*)d_in[4];
    const float* W2  = (const float*)d_in[5];
    const float* b2  = (const float*)d_in[6];
    const float* g2  = (const float*)d_in[7];
    const float* be2 = (const float*)d_in[8];
    const float* W3  = (const float*)d_in[9];
    const float* b3  = (const float*)d_in[10];
    const float* g3  = (const float*)d_in[11];
    const float* be3 = (const float*)d_in[12];
    const float* W4  = (const float*)d_in[13];
    const float* b4  = (const float*)d_in[14];
    const float* g4  = (const float*)d_in[15];
    const float* be4 = (const float*)d_in[16];
    const float* Wh  = (const float*)d_in[17];
    const float* bh  = (const float*)d_in[18];
    const float* u   = (const float*)d_in[19];
    float* out = (float*)d_out;
    u16* wsb = (u16*)d_ws;

    prep_weights<<<dim3(NGROUPS / 256), dim3(256), 0, stream>>>(W1, W2, W3, wsb);

    const int rows = in_sizes[0] / 512;       // 131072
    fused_mlp<<<dim3(rows / 32), dim3(256), 0, stream>>>(
        x, wsb + W1F_OFF, wsb + W2F_OFF, wsb + W3F_OFF, wsb + W3LF_OFF,
        b1, g1, be1, b2, g2, be2, b3, g3, be3,
        W4, b4, g4, be4, Wh, bh, u, out);
}